// Round 1
// baseline (120.223 us; speedup 1.0000x reference)
//
#include <hip/hip_runtime.h>

#define HH 512
#define WW 512
#define HWSZ (HH * WW)
#define NN 32

// Kernel A: K[c,h,w] = bias[c] + sum_{p,q} image[h+p-1, w+q-1] * kw[c, p, q]
// One thread per pixel; computes all 9 channels from one 3x3 patch.
__global__ __launch_bounds__(256) void conv_k_kernel(const float* __restrict__ img,
                                                     const float* __restrict__ kw,
                                                     const float* __restrict__ kb,
                                                     float* __restrict__ K) {
    int idx = blockIdx.x * 256 + threadIdx.x;
    if (idx >= HWSZ) return;
    int h = idx >> 9;        // /512
    int w = idx & 511;

    float p[3][3];
#pragma unroll
    for (int i = 0; i < 3; ++i) {
#pragma unroll
        for (int j = 0; j < 3; ++j) {
            int hh = h + i - 1;
            int ww = w + j - 1;
            p[i][j] = (hh >= 0 && hh < HH && ww >= 0 && ww < WW) ? img[hh * WW + ww] : 0.0f;
        }
    }
#pragma unroll
    for (int c = 0; c < 9; ++c) {
        float acc = kb[c];
#pragma unroll
        for (int i = 0; i < 3; ++i)
#pragma unroll
            for (int j = 0; j < 3; ++j)
                acc = fmaf(p[i][j], kw[c * 9 + i * 3 + j], acc);
        K[c * HWSZ + idx] = acc;
    }
}

// Kernel B: y[n,h,w] = sum_{i,j} x[n, h+i-1, w+j-1] * K[3i+j, h, w]
// Each thread computes 4 consecutive w outputs (float4 store).
// Thread index layout: t = h * (NN * WW/4) + n * (WW/4) + w4i
//   -> concurrent blocks share the same h rows of K across all n (L2-hot).
__global__ __launch_bounds__(256) void apply_kernel(const float* __restrict__ x,
                                                    const float* __restrict__ K,
                                                    float* __restrict__ y) {
    int t = blockIdx.x * 256 + threadIdx.x;
    int w4i = t & 127;          // 7 bits: which group of 4 along W
    int n   = (t >> 7) & 31;    // 5 bits
    int h   = t >> 12;          // 9 bits
    int w4  = w4i * 4;

    const float* xn = x + n * HWSZ;
    float a0 = 0.f, a1 = 0.f, a2 = 0.f, a3 = 0.f;

#pragma unroll
    for (int i = 0; i < 3; ++i) {
        int hh = h + i - 1;
        if (hh < 0 || hh >= HH) continue;
        const float* xr = xn + hh * WW;
        // x values xr[w4-1 .. w4+4] (6 floats), with W-edge zeroing
        float xv[6];
#pragma unroll
        for (int j = 0; j < 6; ++j) {
            int ww = w4 - 1 + j;
            xv[j] = (ww >= 0 && ww < WW) ? xr[ww] : 0.0f;
        }
#pragma unroll
        for (int j = 0; j < 3; ++j) {
            int c = i * 3 + j;
            const float4 kv = *reinterpret_cast<const float4*>(&K[c * HWSZ + h * WW + w4]);
            a0 = fmaf(xv[j + 0], kv.x, a0);
            a1 = fmaf(xv[j + 1], kv.y, a1);
            a2 = fmaf(xv[j + 2], kv.z, a2);
            a3 = fmaf(xv[j + 3], kv.w, a3);
        }
    }
    float4 out = make_float4(a0, a1, a2, a3);
    *reinterpret_cast<float4*>(&y[n * HWSZ + h * WW + w4]) = out;
}

extern "C" void kernel_launch(void* const* d_in, const int* in_sizes, int n_in,
                              void* d_out, int out_size, void* d_ws, size_t ws_size,
                              hipStream_t stream) {
    const float* img = (const float*)d_in[0];   // (1, 512, 512)
    const float* x   = (const float*)d_in[1];   // (32, 1, 512, 512)
    const float* kw  = (const float*)d_in[2];   // (9, 1, 3, 3)
    const float* kb  = (const float*)d_in[3];   // (9,)
    float* y = (float*)d_out;                   // (32, 512, 512)
    float* K = (float*)d_ws;                    // 9 * 512 * 512 floats = 9.4 MB

    // Kernel A: 512*512 pixels / 256 threads
    conv_k_kernel<<<HWSZ / 256, 256, 0, stream>>>(img, kw, kb, K);

    // Kernel B: 32 * 512 * 128 threads / 256
    int total_threads = NN * HH * (WW / 4);
    apply_kernel<<<total_threads / 256, 256, 0, stream>>>(x, K, y);
}

// Round 2
// 101.282 us; speedup vs baseline: 1.1870x; 1.1870x over previous
//
#include <hip/hip_runtime.h>

#define HH 512
#define WW 512
#define HWSZ (HH * WW)
#define NPB 4            // n-planes per block
#define RSTRIDE 520      // row buffer: halo idx 3 (w=-1) .. 516 (w=512)

// One block = one output row h for NPB consecutive n-planes.
// Phase 1: stage image rows in LDS, compute the 9 per-pixel K values into regs.
// Phase 2: per n, double-buffered register prefetch of 3 x-rows -> LDS -> 9-tap apply.
__global__ __launch_bounds__(128) void fused_smblock(const float* __restrict__ img,
                                                     const float* __restrict__ x,
                                                     const float* __restrict__ kw,
                                                     const float* __restrict__ kb,
                                                     float* __restrict__ y) {
    __shared__ float rows[3][RSTRIDE];
    const int tid = threadIdx.x;        // 0..127
    const int h   = blockIdx.x;         // 0..511 (fastest -> adjacent blocks share x rows in L2)
    const int n0  = blockIdx.y * NPB;
    const int w4  = tid * 4;

    // zero the W-halo cells once (never overwritten afterwards)
    if (tid < 3) { rows[tid][3] = 0.0f; rows[tid][516] = 0.0f; }

    const bool vm1 = (h - 1) >= 0;
    const bool vp1 = (h + 1) < HH;

    // ---- phase 1: image rows -> LDS ----
    {
        float4 r0 = vm1 ? *reinterpret_cast<const float4*>(img + (h - 1) * WW + w4) : make_float4(0, 0, 0, 0);
        float4 r1 =       *reinterpret_cast<const float4*>(img + h * WW + w4);
        float4 r2 = vp1 ? *reinterpret_cast<const float4*>(img + (h + 1) * WW + w4) : make_float4(0, 0, 0, 0);
        *reinterpret_cast<float4*>(&rows[0][w4 + 4]) = r0;
        *reinterpret_cast<float4*>(&rows[1][w4 + 4]) = r1;
        *reinterpret_cast<float4*>(&rows[2][w4 + 4]) = r2;
    }
    __syncthreads();

    float iv[3][6];
#pragma unroll
    for (int i = 0; i < 3; ++i) {
        float4 v = *reinterpret_cast<const float4*>(&rows[i][w4 + 4]);
        iv[i][0] = rows[i][w4 + 3];
        iv[i][1] = v.x; iv[i][2] = v.y; iv[i][3] = v.z; iv[i][4] = v.w;
        iv[i][5] = rows[i][w4 + 8];
    }

    // K[c][p] = kb[c] + sum_{i,q} img[h+i-1, w4+p+q-1] * kw[c,i,q]   (p = pixel 0..3)
    float Kr[9][4];
#pragma unroll
    for (int c = 0; c < 9; ++c) {
        float b = kb[c];
#pragma unroll
        for (int p = 0; p < 4; ++p) Kr[c][p] = b;
#pragma unroll
        for (int i = 0; i < 3; ++i)
#pragma unroll
            for (int q = 0; q < 3; ++q) {
                float wv = kw[c * 9 + i * 3 + q];
#pragma unroll
                for (int p = 0; p < 4; ++p)
                    Kr[c][p] = fmaf(iv[i][p + q], wv, Kr[c][p]);
            }
    }
    __syncthreads();   // image rows no longer needed; LDS reused for x

    // ---- phase 2: n-loop with register prefetch (issue-early / write-late) ----
    float4 pr[3];
    {
        const float* base = x + (size_t)n0 * HWSZ;
        pr[0] = vm1 ? *reinterpret_cast<const float4*>(base + (h - 1) * WW + w4) : make_float4(0, 0, 0, 0);
        pr[1] =       *reinterpret_cast<const float4*>(base + h * WW + w4);
        pr[2] = vp1 ? *reinterpret_cast<const float4*>(base + (h + 1) * WW + w4) : make_float4(0, 0, 0, 0);
    }

    for (int nn = 0; nn < NPB; ++nn) {
        *reinterpret_cast<float4*>(&rows[0][w4 + 4]) = pr[0];
        *reinterpret_cast<float4*>(&rows[1][w4 + 4]) = pr[1];
        *reinterpret_cast<float4*>(&rows[2][w4 + 4]) = pr[2];
        __syncthreads();

        if (nn + 1 < NPB) {   // issue next plane's loads; latency hides under compute
            const float* base = x + (size_t)(n0 + nn + 1) * HWSZ;
            pr[0] = vm1 ? *reinterpret_cast<const float4*>(base + (h - 1) * WW + w4) : make_float4(0, 0, 0, 0);
            pr[1] =       *reinterpret_cast<const float4*>(base + h * WW + w4);
            pr[2] = vp1 ? *reinterpret_cast<const float4*>(base + (h + 1) * WW + w4) : make_float4(0, 0, 0, 0);
        }

        float a[4] = {0, 0, 0, 0};
#pragma unroll
        for (int i = 0; i < 3; ++i) {
            float xv[6];
            float4 v = *reinterpret_cast<const float4*>(&rows[i][w4 + 4]);
            xv[0] = rows[i][w4 + 3];
            xv[1] = v.x; xv[2] = v.y; xv[3] = v.z; xv[4] = v.w;
            xv[5] = rows[i][w4 + 8];
#pragma unroll
            for (int j = 0; j < 3; ++j) {
                const int c = i * 3 + j;
#pragma unroll
                for (int p = 0; p < 4; ++p)
                    a[p] = fmaf(xv[p + j], Kr[c][p], a[p]);
            }
        }
        *reinterpret_cast<float4*>(&y[(size_t)(n0 + nn) * HWSZ + h * WW + w4]) =
            make_float4(a[0], a[1], a[2], a[3]);
        __syncthreads();   // rows reused next iteration
    }
}

extern "C" void kernel_launch(void* const* d_in, const int* in_sizes, int n_in,
                              void* d_out, int out_size, void* d_ws, size_t ws_size,
                              hipStream_t stream) {
    const float* img = (const float*)d_in[0];   // (1, 512, 512)
    const float* x   = (const float*)d_in[1];   // (32, 1, 512, 512)
    const float* kw  = (const float*)d_in[2];   // (9, 1, 3, 3)
    const float* kb  = (const float*)d_in[3];   // (9,)
    float* y = (float*)d_out;                   // (32, 512, 512)

    dim3 grid(HH, 32 / NPB);   // h fastest-varying: h-adjacent blocks share x rows in L2
    fused_smblock<<<grid, 128, 0, stream>>>(img, x, kw, kb, y);
}